// Round 8
// baseline (308.651 us; speedup 1.0000x reference)
//
#include <hip/hip_runtime.h>

#define NB  32
#define IDF 768
#define SLN 128
#define QLN 1024
#define NT  24   // IDF/32 k-tiles

typedef __bf16 v8bf __attribute__((ext_vector_type(8)));
typedef __bf16 v4bf __attribute__((ext_vector_type(4)));
typedef float  v4f  __attribute__((ext_vector_type(4)));

#define MFMA16 __builtin_amdgcn_mfma_f32_16x16x32_bf16

__device__ __forceinline__ void split2(float x, __bf16& h, __bf16& l) {
  h = (__bf16)x;
  l = (__bf16)(x - (float)h);
}

// -----------------------------------------------------------------------------
// K0 prep: blocks 0..575 split W -> Wh/Wl; blocks 576..959 transpose+split
// ctx [b][c][s] -> cTh/cTl [b][s][c] (full batch).
// -----------------------------------------------------------------------------
__global__ __launch_bounds__(256) void prep_k(const float* __restrict__ W,
                                              const float* __restrict__ ctx,
                                              __bf16* __restrict__ Wh,
                                              __bf16* __restrict__ Wl,
                                              __bf16* __restrict__ cTh,
                                              __bf16* __restrict__ cTl) {
  const int bid = blockIdx.x, t = threadIdx.x;
  __shared__ float tl[64][133];
  if (bid < 576) {
    int idx = bid * 1024 + t * 4;
    float4 v = *(const float4*)(W + idx);
    float vals[4] = {v.x, v.y, v.z, v.w};
    v4bf h, l;
#pragma unroll
    for (int e = 0; e < 4; ++e) {
      __bf16 hh, ll;
      split2(vals[e], hh, ll);
      h[e] = hh;
      l[e] = ll;
    }
    *(v4bf*)(Wh + idx) = h;
    *(v4bf*)(Wl + idx) = l;
    return;
  }
  const int cid = bid - 576;
  const int b = cid / 12, c0 = (cid % 12) * 64;
#pragma unroll
  for (int j = 0; j < 8; ++j) {  // load 64c x 128s, coalesced
    int u = j * 256 + t;
    int c = u >> 5, s4 = (u & 31) * 4;
    *(float4*)&tl[c][s4] =
        *(const float4*)(ctx + ((size_t)b * IDF + c0 + c) * SLN + s4);
  }
  __syncthreads();
#pragma unroll
  for (int j = 0; j < 8; ++j) {  // write [s][c], split
    int u = j * 256 + t;
    int s = u >> 4, c4 = (u & 15) * 4;
    v4bf h, l;
#pragma unroll
    for (int e = 0; e < 4; ++e) {
      __bf16 hh, ll;
      split2(tl[c4 + e][s], hh, ll);
      h[e] = hh;
      l[e] = ll;
    }
    *(v4bf*)(cTh + ((size_t)b * SLN + s) * IDF + c0 + c4) = h;
    *(v4bf*)(cTl + ((size_t)b * SLN + s) * IDF + c0 + c4) = l;
  }
}

// -----------------------------------------------------------------------------
// K1 proj: D[s][o] = sum_c ctxT[s][c] * W[o][c].  Tile 128s x 32o, grid
// (24, 32) = 768 blocks, 4 waves (ws = w>>1 s-half, wq = w&1 o-16).
// A = ctxT hi/lo via chunk-XOR-swizzled LDS, 2-DEEP reg prefetch (tile t+2
// issued while t is written); B = Wh/Wl frags reg-prefetched 1-deep (L2).
// Outputs STh/STl [b][s][768], Shv [b][o][s].
// -----------------------------------------------------------------------------
__global__ __launch_bounds__(256) void proj_k(const __bf16* __restrict__ cTh,
                                              const __bf16* __restrict__ cTl,
                                              const __bf16* __restrict__ Wh,
                                              const __bf16* __restrict__ Wl,
                                              __bf16* __restrict__ STh,
                                              __bf16* __restrict__ STl,
                                              __bf16* __restrict__ Shv) {
  const int b = blockIdx.y, o0 = blockIdx.x * 32;
  const int t = threadIdx.x, w = t >> 6, lane = t & 63;
  const int lr = lane & 15, lg = lane >> 4;
  const int ws = w >> 1, wq = w & 1;
  __shared__ __bf16 AhL[128][32];
  __shared__ __bf16 AlL[128][32];

  v4f acc[4];
#pragma unroll
  for (int fr = 0; fr < 4; ++fr) acc[fr] = (v4f){0.f, 0.f, 0.f, 0.f};

  const int ra = t >> 1, ca0 = (t & 1) * 2;
  const int swA = (ra >> 1) & 3;
  const int pa0 = (ca0 ^ swA) * 8, pa1 = ((ca0 + 1) ^ swA) * 8;
  const __bf16* pAh = cTh + ((size_t)b * SLN + ra) * IDF + ca0 * 8;
  const __bf16* pAl = cTl + ((size_t)b * SLN + ra) * IDF + ca0 * 8;
  const size_t wOff = (size_t)(o0 + wq * 16 + lr) * IDF + lg * 8;

  // 2-deep A prefetch sets
  uint4 sAh0[2], sAh1[2], sAl0[2], sAl1[2];
  v8bf bhc, blc, bhn, bln;
#pragma unroll
  for (int p = 0; p < 2; ++p) {
    sAh0[p] = *(const uint4*)(pAh + p * 32);
    sAh1[p] = *(const uint4*)(pAh + p * 32 + 8);
    sAl0[p] = *(const uint4*)(pAl + p * 32);
    sAl1[p] = *(const uint4*)(pAl + p * 32 + 8);
  }
  bhc = *(const v8bf*)(Wh + wOff);
  blc = *(const v8bf*)(Wl + wOff);

  for (int it = 0; it < NT; ++it) {
    const int p = it & 1;
    __syncthreads();
    *(uint4*)&AhL[ra][pa0] = sAh0[p];
    *(uint4*)&AhL[ra][pa1] = sAh1[p];
    *(uint4*)&AlL[ra][pa0] = sAl0[p];
    *(uint4*)&AlL[ra][pa1] = sAl1[p];
    if (it + 2 < NT) {
      sAh0[p] = *(const uint4*)(pAh + (it + 2) * 32);
      sAh1[p] = *(const uint4*)(pAh + (it + 2) * 32 + 8);
      sAl0[p] = *(const uint4*)(pAl + (it + 2) * 32);
      sAl1[p] = *(const uint4*)(pAl + (it + 2) * 32 + 8);
    }
    if (it + 1 < NT) {
      bhn = *(const v8bf*)(Wh + wOff + (it + 1) * 32);
      bln = *(const v8bf*)(Wl + wOff + (it + 1) * 32);
    }
    __syncthreads();

#pragma unroll
    for (int fr = 0; fr < 4; ++fr) {
      const int r = ws * 64 + fr * 16 + lr;
      const int pp = (lg ^ ((r >> 1) & 3)) * 8;
      v8bf ah = *(const v8bf*)&AhL[r][pp];
      v8bf al = *(const v8bf*)&AlL[r][pp];
      acc[fr] = MFMA16(ah, bhc, acc[fr], 0, 0, 0);
      acc[fr] = MFMA16(ah, blc, acc[fr], 0, 0, 0);
      acc[fr] = MFMA16(al, bhc, acc[fr], 0, 0, 0);
    }
    bhc = bhn;
    blc = bln;
  }

  const int o = o0 + wq * 16 + lr;
#pragma unroll
  for (int fr = 0; fr < 4; ++fr) {
    __bf16 hp[4];
#pragma unroll
    for (int r = 0; r < 4; ++r) {
      int s = ws * 64 + fr * 16 + lg * 4 + r;
      __bf16 h, l;
      split2(acc[fr][r], h, l);
      STh[((size_t)b * SLN + s) * IDF + o] = h;
      STl[((size_t)b * SLN + s) * IDF + o] = l;
      hp[r] = h;
    }
    *(v4bf*)(Shv + ((size_t)b * IDF + o) * SLN + ws * 64 + fr * 16 + lg * 4) =
        (v4bf){hp[0], hp[1], hp[2], hp[3]};
  }
}

// -----------------------------------------------------------------------------
// K2 qk: 512 threads = 8 waves; wave w: wq = w&3 (q-16), sh = w>>2 (s-half 64).
// Threads 0..255 stage A-hi, 256..511 stage A-lo (XOR-swizzled map); all
// threads stage input f32 tile. 2-DEEP reg prefetch. Cross-wave softmax via
// LDS. Writes attn_out + Ppv.
// -----------------------------------------------------------------------------
__global__ __launch_bounds__(512) void qk_k(const float* __restrict__ input,
                                            const __bf16* __restrict__ STh,
                                            const __bf16* __restrict__ STl,
                                            const int* __restrict__ mask,
                                            __bf16* __restrict__ Ppv,
                                            float* __restrict__ attn_out) {
  const int b = blockIdx.y, q0 = blockIdx.x * 64;
  const int t = threadIdx.x, w = t >> 6, lane = t & 63;
  const int lr = lane & 15, lg = lane >> 4;
  const int wq = w & 3, sh = w >> 2;
  __shared__ __bf16 AhL[128][32];
  __shared__ __bf16 AlL[128][32];
  __shared__ __align__(16) float tiL[32][66];
  __shared__ float msk[SLN];
  __shared__ float redm[2][4][16], reds[2][4][16];
  if (t < SLN) msk[t] = -10000.0f * (float)mask[b * SLN + t];

  v4f acc[4];
#pragma unroll
  for (int fr = 0; fr < 4; ++fr) acc[fr] = (v4f){0.f, 0.f, 0.f, 0.f};

  const int u = t & 255;
  const int ra = u >> 1, ca0 = (u & 1) * 2;
  const int swA = (ra >> 1) & 3;
  const int pa0 = (ca0 ^ swA) * 8, pa1 = ((ca0 + 1) ^ swA) * 8;
  const __bf16* pA =
      (((t < 256) ? STh : STl) + ((size_t)b * SLN + ra) * IDF) + ca0 * 8;
  __bf16* dA = (t < 256) ? &AhL[0][0] : &AlL[0][0];
  __bf16* dA0 = dA + ra * 32 + pa0;
  __bf16* dA1 = dA + ra * 32 + pa1;
  const int rb = t >> 4, cb = (t & 15) * 4;
  const float* pIn = input + ((size_t)b * IDF + rb) * QLN + q0 + cb;

  // 2-deep prefetch sets
  uint4 sA0[2], sA1[2];
  float4 sT[2];
#pragma unroll
  for (int p = 0; p < 2; ++p) {
    sA0[p] = *(const uint4*)(pA + p * 32);
    sA1[p] = *(const uint4*)(pA + p * 32 + 8);
    sT[p] = *(const float4*)(pIn + (size_t)p * 32 * QLN);
  }

  for (int it = 0; it < NT; ++it) {
    const int p = it & 1;
    __syncthreads();
    *(uint4*)dA0 = sA0[p];
    *(uint4*)dA1 = sA1[p];
    *(float2*)&tiL[rb][cb]     = make_float2(sT[p].x, sT[p].y);
    *(float2*)&tiL[rb][cb + 2] = make_float2(sT[p].z, sT[p].w);
    if (it + 2 < NT) {
      sA0[p] = *(const uint4*)(pA + (it + 2) * 32);
      sA1[p] = *(const uint4*)(pA + (it + 2) * 32 + 8);
      sT[p] = *(const float4*)(pIn + (size_t)(it + 2) * 32 * QLN);
    }
    __syncthreads();

    v8bf bh, bl;
#pragma unroll
    for (int e = 0; e < 8; ++e) {  // 2-way banks (stride 66 words)
      __bf16 h, l;
      split2(tiL[lg * 8 + e][wq * 16 + lr], h, l);
      bh[e] = h;
      bl[e] = l;
    }
#pragma unroll
    for (int fr = 0; fr < 4; ++fr) {
      const int r = sh * 64 + fr * 16 + lr;
      const int pp = (lg ^ ((r >> 1) & 3)) * 8;
      v8bf ah = *(const v8bf*)&AhL[r][pp];
      v8bf al = *(const v8bf*)&AlL[r][pp];
      acc[fr] = MFMA16(ah, bh, acc[fr], 0, 0, 0);
      acc[fr] = MFMA16(ah, bl, acc[fr], 0, 0, 0);
      acc[fr] = MFMA16(al, bh, acc[fr], 0, 0, 0);
    }
  }

  // softmax over s=128 for q = q0 + wq*16 + lr; wave owns 64 s (half sh)
  const int q = q0 + wq * 16 + lr;
  float mx = -3.0e38f;
#pragma unroll
  for (int fr = 0; fr < 4; ++fr)
#pragma unroll
    for (int r = 0; r < 4; ++r) {
      acc[fr][r] += msk[sh * 64 + fr * 16 + lg * 4 + r];
      mx = fmaxf(mx, acc[fr][r]);
    }
  mx = fmaxf(mx, __shfl_xor(mx, 16));
  mx = fmaxf(mx, __shfl_xor(mx, 32));
  if (lg == 0) redm[sh][wq][lr] = mx;
  __syncthreads();
  mx = fmaxf(redm[0][wq][lr], redm[1][wq][lr]);
  float sum = 0.f;
#pragma unroll
  for (int fr = 0; fr < 4; ++fr)
#pragma unroll
    for (int r = 0; r < 4; ++r) {
      float e = __expf(acc[fr][r] - mx);
      acc[fr][r] = e;
      sum += e;
    }
  sum += __shfl_xor(sum, 16);
  sum += __shfl_xor(sum, 32);
  if (lg == 0) reds[sh][wq][lr] = sum;
  __syncthreads();
  const float inv = 1.0f / (reds[0][wq][lr] + reds[1][wq][lr]);
#pragma unroll
  for (int fr = 0; fr < 4; ++fr) {
    __bf16 hp[4];
#pragma unroll
    for (int r = 0; r < 4; ++r) {
      float p = acc[fr][r] * inv;
      attn_out[((size_t)b * SLN + sh * 64 + fr * 16 + lg * 4 + r) * QLN + q] = p;
      hp[r] = (__bf16)p;
    }
    *(v4bf*)(Ppv + ((size_t)b * QLN + q) * SLN + sh * 64 + fr * 16 + lg * 4) =
        (v4bf){hp[0], hp[1], hp[2], hp[3]};
  }
}

// -----------------------------------------------------------------------------
// K3 pv: wc[i][q] = sum_s Shv[i][s] * P[q][s].  Grid (8,6,32) = 1536 blocks.
// SWAPPED MFMA roles: A = P rows (q), B = Shv rows (i) => D[q][i]; lane holds
// 4 consecutive q for fixed i => float4 stores into wc[i][q] (q-contiguous).
// Per-element k-order identical to previous version => bit-identical values.
// -----------------------------------------------------------------------------
__global__ __launch_bounds__(256) void pv_k(const __bf16* __restrict__ Shv,
                                            const __bf16* __restrict__ Ppv,
                                            float* __restrict__ wc) {
  const int b = blockIdx.z, i0 = blockIdx.y * 128, q0 = blockIdx.x * 128;
  const int t = threadIdx.x, w = t >> 6, lane = t & 63;
  const int lr = lane & 15, lg = lane >> 4;
  __shared__ __align__(16) __bf16 PL[128][136];
  {
    const int pr = t >> 1, pc = (t & 1) * 64;
    const __bf16* src = Ppv + ((size_t)b * QLN + q0 + pr) * SLN + pc;
#pragma unroll
    for (int j = 0; j < 8; ++j)
      *(uint4*)&PL[pr][pc + j * 8] = *(const uint4*)(src + j * 8);
  }
  __syncthreads();
  v4f acc[2][8];
#pragma unroll
  for (int fr = 0; fr < 2; ++fr)
#pragma unroll
    for (int fc = 0; fc < 8; ++fc) acc[fr][fc] = (v4f){0.f, 0.f, 0.f, 0.f};
#pragma unroll
  for (int kt = 0; kt < 4; ++kt) {
    const int k0 = kt * 32 + lg * 8;
    v8bf a0 = *(const v8bf*)&PL[w * 32 + lr][k0];       // A: P row q
    v8bf a1 = *(const v8bf*)&PL[w * 32 + 16 + lr][k0];
#pragma unroll
    for (int fc = 0; fc < 8; ++fc) {
      v8bf bb = *(const v8bf*)(Shv +
          ((size_t)b * IDF + i0 + fc * 16 + lr) * SLN + k0);  // B: Shv row i
      acc[0][fc] = MFMA16(a0, bb, acc[0][fc], 0, 0, 0);
      acc[1][fc] = MFMA16(a1, bb, acc[1][fc], 0, 0, 0);
    }
  }
#pragma unroll
  for (int fr = 0; fr < 2; ++fr)
#pragma unroll
    for (int fc = 0; fc < 8; ++fc) {
      const int i = i0 + fc * 16 + lr;
      const int q = q0 + w * 32 + fr * 16 + lg * 4;
      float4 v = make_float4(acc[fr][fc][0], acc[fr][fc][1],
                             acc[fr][fc][2], acc[fr][fc][3]);
      *(float4*)(wc + ((size_t)b * IDF + i) * QLN + q) = v;
    }
}

// -----------------------------------------------------------------------------
extern "C" void kernel_launch(void* const* d_in, const int* in_sizes, int n_in,
                              void* d_out, int out_size, void* d_ws, size_t ws_size,
                              hipStream_t stream) {
  const float* input   = (const float*)d_in[0];  // [B, IDF, 32, 32]
  const float* context = (const float*)d_in[1];  // [B, CDF, SL]
  const int*   mask    = (const int*)d_in[2];    // [B, SL]
  const float* w_conv  = (const float*)d_in[3];  // [IDF, CDF]

  float* out      = (float*)d_out;
  float* wc       = out;                          // [B, IDF, QL]
  float* attn_out = out + (size_t)NB * IDF * QLN; // [B, SL, QL]

  // Scratch plan:
  //  - wc output region (100.66 MB, written only by pv at the END) doubles as
  //    scratch for cTh|cTl|Wh|Wl (14.9 MB), all dead before pv runs.
  //  - d_ws: Ppv | STh | STl | Shv = 13,631,488 bf16 = 27,262,976 B
  //    (< 29,360,128 B proven available).
  const size_t SE = (size_t)NB * SLN * IDF;  // 3,145,728
  const size_t WE = (size_t)IDF * IDF;       // 589,824
  const size_t PE = (size_t)NB * QLN * SLN;  // 4,194,304
  __bf16* wsb = (__bf16*)d_ws;
  __bf16* Ppv = wsb;
  __bf16* STh = wsb + PE;
  __bf16* STl = STh + SE;
  __bf16* Shv = STl + SE;
  __bf16* scr = (__bf16*)wc;  // scratch in output region
  __bf16* cTh = scr;
  __bf16* cTl = cTh + SE;
  __bf16* Wh  = cTl + SE;
  __bf16* Wl  = Wh + WE;

  prep_k<<<960, 256, 0, stream>>>(w_conv, context, Wh, Wl, cTh, cTl);
  proj_k<<<dim3(24, NB), 256, 0, stream>>>(cTh, cTl, Wh, Wl, STh, STl, Shv);
  qk_k<<<dim3(16, NB), 512, 0, stream>>>(input, STh, STl, mask, Ppv, attn_out);
  pv_k<<<dim3(8, 6, NB), 256, 0, stream>>>(Shv, Ppv, wc);
}

// Round 9
// 133.572 us; speedup vs baseline: 2.3108x; 2.3108x over previous
//
#include <hip/hip_runtime.h>

#define NB  32
#define IDF 768
#define SLN 128
#define QLN 1024
#define NT  24   // IDF/32 k-tiles (even)

typedef __bf16 v8bf __attribute__((ext_vector_type(8)));
typedef __bf16 v4bf __attribute__((ext_vector_type(4)));
typedef float  v4f  __attribute__((ext_vector_type(4)));

#define MFMA16 __builtin_amdgcn_mfma_f32_16x16x32_bf16

__device__ __forceinline__ void split2(float x, __bf16& h, __bf16& l) {
  h = (__bf16)x;
  l = (__bf16)(x - (float)h);
}

// -----------------------------------------------------------------------------
// K0 prep: blocks 0..575 split W -> Wh/Wl; blocks 576..959 transpose+split
// ctx [b][c][s] -> cTh/cTl [b][s][c] (full batch).
// -----------------------------------------------------------------------------
__global__ __launch_bounds__(256) void prep_k(const float* __restrict__ W,
                                              const float* __restrict__ ctx,
                                              __bf16* __restrict__ Wh,
                                              __bf16* __restrict__ Wl,
                                              __bf16* __restrict__ cTh,
                                              __bf16* __restrict__ cTl) {
  const int bid = blockIdx.x, t = threadIdx.x;
  __shared__ float tl[64][133];
  if (bid < 576) {
    int idx = bid * 1024 + t * 4;
    float4 v = *(const float4*)(W + idx);
    float vals[4] = {v.x, v.y, v.z, v.w};
    v4bf h, l;
#pragma unroll
    for (int e = 0; e < 4; ++e) {
      __bf16 hh, ll;
      split2(vals[e], hh, ll);
      h[e] = hh;
      l[e] = ll;
    }
    *(v4bf*)(Wh + idx) = h;
    *(v4bf*)(Wl + idx) = l;
    return;
  }
  const int cid = bid - 576;
  const int b = cid / 12, c0 = (cid % 12) * 64;
#pragma unroll
  for (int j = 0; j < 8; ++j) {  // load 64c x 128s, coalesced
    int u = j * 256 + t;
    int c = u >> 5, s4 = (u & 31) * 4;
    *(float4*)&tl[c][s4] =
        *(const float4*)(ctx + ((size_t)b * IDF + c0 + c) * SLN + s4);
  }
  __syncthreads();
#pragma unroll
  for (int j = 0; j < 8; ++j) {  // write [s][c], split
    int u = j * 256 + t;
    int s = u >> 4, c4 = (u & 15) * 4;
    v4bf h, l;
#pragma unroll
    for (int e = 0; e < 4; ++e) {
      __bf16 hh, ll;
      split2(tl[c4 + e][s], hh, ll);
      h[e] = hh;
      l[e] = ll;
    }
    *(v4bf*)(cTh + ((size_t)b * SLN + s) * IDF + c0 + c4) = h;
    *(v4bf*)(cTl + ((size_t)b * SLN + s) * IDF + c0 + c4) = l;
  }
}

// -----------------------------------------------------------------------------
// K1 proj: D[s][o] = sum_c ctxT[s][c] * W[o][c].  Tile 128s x 32o, grid
// (24, 32), 4 waves (ws = w>>1 s-half, wq = w&1 o-16).
// 2-deep reg prefetch with NAMED sets (a = even tiles, b = odd tiles) and a
// manually 2x-unrolled loop -> all indices compile-time (rule: runtime-indexed
// register arrays spill to scratch). A via chunk-XOR-swizzled LDS; B = Wh/Wl
// frags 1-deep from L2. Outputs STh/STl [b][s][768], Shv [b][o][s].
// -----------------------------------------------------------------------------
__global__ __launch_bounds__(256) void proj_k(const __bf16* __restrict__ cTh,
                                              const __bf16* __restrict__ cTl,
                                              const __bf16* __restrict__ Wh,
                                              const __bf16* __restrict__ Wl,
                                              __bf16* __restrict__ STh,
                                              __bf16* __restrict__ STl,
                                              __bf16* __restrict__ Shv) {
  const int b = blockIdx.y, o0 = blockIdx.x * 32;
  const int t = threadIdx.x, w = t >> 6, lane = t & 63;
  const int lr = lane & 15, lg = lane >> 4;
  const int ws = w >> 1, wq = w & 1;
  __shared__ __bf16 AhL[128][32];
  __shared__ __bf16 AlL[128][32];

  v4f acc[4];
#pragma unroll
  for (int fr = 0; fr < 4; ++fr) acc[fr] = (v4f){0.f, 0.f, 0.f, 0.f};

  const int ra = t >> 1, ca0 = (t & 1) * 2;
  const int swA = (ra >> 1) & 3;
  const int pa0 = (ca0 ^ swA) * 8, pa1 = ((ca0 + 1) ^ swA) * 8;
  const __bf16* pAh = cTh + ((size_t)b * SLN + ra) * IDF + ca0 * 8;
  const __bf16* pAl = cTl + ((size_t)b * SLN + ra) * IDF + ca0 * 8;
  const size_t wOff = (size_t)(o0 + wq * 16 + lr) * IDF + lg * 8;

  // named 2-deep prefetch sets
  uint4 aAh0, aAh1, aAl0, aAl1;   // even tiles
  uint4 bAh0, bAh1, bAl0, bAl1;   // odd tiles
  v8bf bhc, blc, bhn, bln;
  aAh0 = *(const uint4*)(pAh);
  aAh1 = *(const uint4*)(pAh + 8);
  aAl0 = *(const uint4*)(pAl);
  aAl1 = *(const uint4*)(pAl + 8);
  bAh0 = *(const uint4*)(pAh + 32);
  bAh1 = *(const uint4*)(pAh + 40);
  bAl0 = *(const uint4*)(pAl + 32);
  bAl1 = *(const uint4*)(pAl + 40);
  bhc = *(const v8bf*)(Wh + wOff);
  blc = *(const v8bf*)(Wl + wOff);

#define PROJ_BODY(S0, S1, S2, S3, IT)                                          \
  {                                                                            \
    __syncthreads();                                                           \
    *(uint4*)&AhL[ra][pa0] = S0;                                               \
    *(uint4*)&AhL[ra][pa1] = S1;                                               \
    *(uint4*)&AlL[ra][pa0] = S2;                                               \
    *(uint4*)&AlL[ra][pa1] = S3;                                               \
    if ((IT) + 2 < NT) {                                                       \
      S0 = *(const uint4*)(pAh + ((IT) + 2) * 32);                             \
      S1 = *(const uint4*)(pAh + ((IT) + 2) * 32 + 8);                         \
      S2 = *(const uint4*)(pAl + ((IT) + 2) * 32);                             \
      S3 = *(const uint4*)(pAl + ((IT) + 2) * 32 + 8);                         \
    }                                                                          \
    if ((IT) + 1 < NT) {                                                       \
      bhn = *(const v8bf*)(Wh + wOff + ((IT) + 1) * 32);                       \
      bln = *(const v8bf*)(Wl + wOff + ((IT) + 1) * 32);                       \
    }                                                                          \
    __syncthreads();                                                           \
    _Pragma("unroll") for (int fr = 0; fr < 4; ++fr) {                         \
      const int r = ws * 64 + fr * 16 + lr;                                    \
      const int pp = (lg ^ ((r >> 1) & 3)) * 8;                                \
      v8bf ah = *(const v8bf*)&AhL[r][pp];                                     \
      v8bf al = *(const v8bf*)&AlL[r][pp];                                     \
      acc[fr] = MFMA16(ah, bhc, acc[fr], 0, 0, 0);                             \
      acc[fr] = MFMA16(ah, blc, acc[fr], 0, 0, 0);                             \
      acc[fr] = MFMA16(al, bhc, acc[fr], 0, 0, 0);                             \
    }                                                                          \
    bhc = bhn;                                                                 \
    blc = bln;                                                                 \
  }

  for (int it2 = 0; it2 < NT / 2; ++it2) {
    const int itE = it2 * 2;
    PROJ_BODY(aAh0, aAh1, aAl0, aAl1, itE);
    PROJ_BODY(bAh0, bAh1, bAl0, bAl1, itE + 1);
  }
#undef PROJ_BODY

  const int o = o0 + wq * 16 + lr;
#pragma unroll
  for (int fr = 0; fr < 4; ++fr) {
    __bf16 hp[4];
#pragma unroll
    for (int r = 0; r < 4; ++r) {
      int s = ws * 64 + fr * 16 + lg * 4 + r;
      __bf16 h, l;
      split2(acc[fr][r], h, l);
      STh[((size_t)b * SLN + s) * IDF + o] = h;
      STl[((size_t)b * SLN + s) * IDF + o] = l;
      hp[r] = h;
    }
    *(v4bf*)(Shv + ((size_t)b * IDF + o) * SLN + ws * 64 + fr * 16 + lg * 4) =
        (v4bf){hp[0], hp[1], hp[2], hp[3]};
  }
}

// -----------------------------------------------------------------------------
// K2 qk: 512 threads = 8 waves; wave w: wq = w&3 (q-16), sh = w>>2 (s-half 64).
// Threads 0..255 stage A-hi, 256..511 stage A-lo (XOR-swizzled map); all
// threads stage input f32 tile. 2-deep reg prefetch with NAMED sets + 2x
// unrolled loop (static indexing). Cross-wave softmax via LDS.
// -----------------------------------------------------------------------------
__global__ __launch_bounds__(512) void qk_k(const float* __restrict__ input,
                                            const __bf16* __restrict__ STh,
                                            const __bf16* __restrict__ STl,
                                            const int* __restrict__ mask,
                                            __bf16* __restrict__ Ppv,
                                            float* __restrict__ attn_out) {
  const int b = blockIdx.y, q0 = blockIdx.x * 64;
  const int t = threadIdx.x, w = t >> 6, lane = t & 63;
  const int lr = lane & 15, lg = lane >> 4;
  const int wq = w & 3, sh = w >> 2;
  __shared__ __bf16 AhL[128][32];
  __shared__ __bf16 AlL[128][32];
  __shared__ __align__(16) float tiL[32][66];
  __shared__ float msk[SLN];
  __shared__ float redm[2][4][16], reds[2][4][16];
  if (t < SLN) msk[t] = -10000.0f * (float)mask[b * SLN + t];

  v4f acc[4];
#pragma unroll
  for (int fr = 0; fr < 4; ++fr) acc[fr] = (v4f){0.f, 0.f, 0.f, 0.f};

  const int u = t & 255;
  const int ra = u >> 1, ca0 = (u & 1) * 2;
  const int swA = (ra >> 1) & 3;
  const int pa0 = (ca0 ^ swA) * 8, pa1 = ((ca0 + 1) ^ swA) * 8;
  const __bf16* pA =
      (((t < 256) ? STh : STl) + ((size_t)b * SLN + ra) * IDF) + ca0 * 8;
  __bf16* dA = (t < 256) ? &AhL[0][0] : &AlL[0][0];
  __bf16* dA0 = dA + ra * 32 + pa0;
  __bf16* dA1 = dA + ra * 32 + pa1;
  const int rb = t >> 4, cb = (t & 15) * 4;
  const float* pIn = input + ((size_t)b * IDF + rb) * QLN + q0 + cb;

  // named 2-deep prefetch sets
  uint4 aA0, aA1, bA0, bA1;
  float4 aT, bT;
  aA0 = *(const uint4*)(pA);
  aA1 = *(const uint4*)(pA + 8);
  aT  = *(const float4*)(pIn);
  bA0 = *(const uint4*)(pA + 32);
  bA1 = *(const uint4*)(pA + 40);
  bT  = *(const float4*)(pIn + (size_t)32 * QLN);

#define QK_BODY(S0, S1, ST_, IT)                                               \
  {                                                                            \
    __syncthreads();                                                           \
    *(uint4*)dA0 = S0;                                                         \
    *(uint4*)dA1 = S1;                                                         \
    *(float2*)&tiL[rb][cb]     = make_float2(ST_.x, ST_.y);                    \
    *(float2*)&tiL[rb][cb + 2] = make_float2(ST_.z, ST_.w);                    \
    if ((IT) + 2 < NT) {                                                       \
      S0 = *(const uint4*)(pA + ((IT) + 2) * 32);                              \
      S1 = *(const uint4*)(pA + ((IT) + 2) * 32 + 8);                          \
      ST_ = *(const float4*)(pIn + (size_t)((IT) + 2) * 32 * QLN);             \
    }                                                                          \
    __syncthreads();                                                           \
    v8bf bh, bl;                                                               \
    _Pragma("unroll") for (int e = 0; e < 8; ++e) {                            \
      __bf16 h, l;                                                             \
      split2(tiL[lg * 8 + e][wq * 16 + lr], h, l);                             \
      bh[e] = h;                                                               \
      bl[e] = l;                                                               \
    }                                                                          \
    _Pragma("unroll") for (int fr = 0; fr < 4; ++fr) {                         \
      const int r = sh * 64 + fr * 16 + lr;                                    \
      const int pp = (lg ^ ((r >> 1) & 3)) * 8;                                \
      v8bf ah = *(const v8bf*)&AhL[r][pp];                                     \
      v8bf al = *(const v8bf*)&AlL[r][pp];                                     \
      acc[fr] = MFMA16(ah, bh, acc[fr], 0, 0, 0);                              \
      acc[fr] = MFMA16(ah, bl, acc[fr], 0, 0, 0);                              \
      acc[fr] = MFMA16(al, bh, acc[fr], 0, 0, 0);                              \
    }                                                                          \
  }

  for (int it2 = 0; it2 < NT / 2; ++it2) {
    const int itE = it2 * 2;
    QK_BODY(aA0, aA1, aT, itE);
    QK_BODY(bA0, bA1, bT, itE + 1);
  }
#undef QK_BODY

  // softmax over s=128 for q = q0 + wq*16 + lr; wave owns 64 s (half sh)
  const int q = q0 + wq * 16 + lr;
  float mx = -3.0e38f;
#pragma unroll
  for (int fr = 0; fr < 4; ++fr)
#pragma unroll
    for (int r = 0; r < 4; ++r) {
      acc[fr][r] += msk[sh * 64 + fr * 16 + lg * 4 + r];
      mx = fmaxf(mx, acc[fr][r]);
    }
  mx = fmaxf(mx, __shfl_xor(mx, 16));
  mx = fmaxf(mx, __shfl_xor(mx, 32));
  if (lg == 0) redm[sh][wq][lr] = mx;
  __syncthreads();
  mx = fmaxf(redm[0][wq][lr], redm[1][wq][lr]);
  float sum = 0.f;
#pragma unroll
  for (int fr = 0; fr < 4; ++fr)
#pragma unroll
    for (int r = 0; r < 4; ++r) {
      float e = __expf(acc[fr][r] - mx);
      acc[fr][r] = e;
      sum += e;
    }
  sum += __shfl_xor(sum, 16);
  sum += __shfl_xor(sum, 32);
  if (lg == 0) reds[sh][wq][lr] = sum;
  __syncthreads();
  const float inv = 1.0f / (reds[0][wq][lr] + reds[1][wq][lr]);
#pragma unroll
  for (int fr = 0; fr < 4; ++fr) {
    __bf16 hp[4];
#pragma unroll
    for (int r = 0; r < 4; ++r) {
      float p = acc[fr][r] * inv;
      attn_out[((size_t)b * SLN + sh * 64 + fr * 16 + lg * 4 + r) * QLN + q] = p;
      hp[r] = (__bf16)p;
    }
    *(v4bf*)(Ppv + ((size_t)b * QLN + q) * SLN + sh * 64 + fr * 16 + lg * 4) =
        (v4bf){hp[0], hp[1], hp[2], hp[3]};
  }
}

// -----------------------------------------------------------------------------
// K3 pv: wc[i][q] = sum_s Shv[i][s] * P[q][s].  Grid (8,6,32) = 1536 blocks.
// A = P rows (q), B = Shv rows (i) => D[q][i]; lane holds 4 consecutive q for
// fixed i => float4 stores into wc[i][q]. k-order identical => bit-identical.
// -----------------------------------------------------------------------------
__global__ __launch_bounds__(256) void pv_k(const __bf16* __restrict__ Shv,
                                            const __bf16* __restrict__ Ppv,
                                            float* __restrict__ wc) {
  const int b = blockIdx.z, i0 = blockIdx.y * 128, q0 = blockIdx.x * 128;
  const int t = threadIdx.x, w = t >> 6, lane = t & 63;
  const int lr = lane & 15, lg = lane >> 4;
  __shared__ __align__(16) __bf16 PL[128][136];
  {
    const int pr = t >> 1, pc = (t & 1) * 64;
    const __bf16* src = Ppv + ((size_t)b * QLN + q0 + pr) * SLN + pc;
#pragma unroll
    for (int j = 0; j < 8; ++j)
      *(uint4*)&PL[pr][pc + j * 8] = *(const uint4*)(src + j * 8);
  }
  __syncthreads();
  v4f acc[2][8];
#pragma unroll
  for (int fr = 0; fr < 2; ++fr)
#pragma unroll
    for (int fc = 0; fc < 8; ++fc) acc[fr][fc] = (v4f){0.f, 0.f, 0.f, 0.f};
#pragma unroll
  for (int kt = 0; kt < 4; ++kt) {
    const int k0 = kt * 32 + lg * 8;
    v8bf a0 = *(const v8bf*)&PL[w * 32 + lr][k0];       // A: P row q
    v8bf a1 = *(const v8bf*)&PL[w * 32 + 16 + lr][k0];
#pragma unroll
    for (int fc = 0; fc < 8; ++fc) {
      v8bf bb = *(const v8bf*)(Shv +
          ((size_t)b * IDF + i0 + fc * 16 + lr) * SLN + k0);  // B: Shv row i
      acc[0][fc] = MFMA16(a0, bb, acc[0][fc], 0, 0, 0);
      acc[1][fc] = MFMA16(a1, bb, acc[1][fc], 0, 0, 0);
    }
  }
#pragma unroll
  for (int fr = 0; fr < 2; ++fr)
#pragma unroll
    for (int fc = 0; fc < 8; ++fc) {
      const int i = i0 + fc * 16 + lr;
      const int q = q0 + w * 32 + fr * 16 + lg * 4;
      float4 v = make_float4(acc[fr][fc][0], acc[fr][fc][1],
                             acc[fr][fc][2], acc[fr][fc][3]);
      *(float4*)(wc + ((size_t)b * IDF + i) * QLN + q) = v;
    }
}

// -----------------------------------------------------------------------------
extern "C" void kernel_launch(void* const* d_in, const int* in_sizes, int n_in,
                              void* d_out, int out_size, void* d_ws, size_t ws_size,
                              hipStream_t stream) {
  const float* input   = (const float*)d_in[0];  // [B, IDF, 32, 32]
  const float* context = (const float*)d_in[1];  // [B, CDF, SL]
  const int*   mask    = (const int*)d_in[2];    // [B, SL]
  const float* w_conv  = (const float*)d_in[3];  // [IDF, CDF]

  float* out      = (float*)d_out;
  float* wc       = out;                          // [B, IDF, QL]
  float* attn_out = out + (size_t)NB * IDF * QLN; // [B, SL, QL]

  // Scratch plan:
  //  - wc output region (100.66 MB, written only by pv at the END) doubles as
  //    scratch for cTh|cTl|Wh|Wl (14.9 MB), all dead before pv runs.
  //  - d_ws: Ppv | STh | STl | Shv = 13,631,488 bf16 = 27,262,976 B
  //    (< 29,360,128 B proven available).
  const size_t SE = (size_t)NB * SLN * IDF;  // 3,145,728
  const size_t WE = (size_t)IDF * IDF;       // 589,824
  const size_t PE = (size_t)NB * QLN * SLN;  // 4,194,304
  __bf16* wsb = (__bf16*)d_ws;
  __bf16* Ppv = wsb;
  __bf16* STh = wsb + PE;
  __bf16* STl = STh + SE;
  __bf16* Shv = STl + SE;
  __bf16* scr = (__bf16*)wc;  // scratch in output region
  __bf16* cTh = scr;
  __bf16* cTl = cTh + SE;
  __bf16* Wh  = cTl + SE;
  __bf16* Wl  = Wh + WE;

  prep_k<<<960, 256, 0, stream>>>(w_conv, context, Wh, Wl, cTh, cTl);
  proj_k<<<dim3(24, NB), 256, 0, stream>>>(cTh, cTl, Wh, Wl, STh, STl, Shv);
  qk_k<<<dim3(16, NB), 512, 0, stream>>>(input, STh, STl, mask, Ppv, attn_out);
  pv_k<<<dim3(8, 6, NB), 256, 0, stream>>>(Shv, Ppv, wc);
}

// Round 10
// 110.630 us; speedup vs baseline: 2.7899x; 1.2074x over previous
//
#include <hip/hip_runtime.h>

#define NB  32
#define IDF 768
#define SLN 128
#define QLN 1024
#define NT  24   // IDF/32 k-tiles (even)

typedef __bf16 v8bf __attribute__((ext_vector_type(8)));
typedef __bf16 v4bf __attribute__((ext_vector_type(4)));
typedef float  v4f  __attribute__((ext_vector_type(4)));

#define MFMA16 __builtin_amdgcn_mfma_f32_16x16x32_bf16

__device__ __forceinline__ void split2(float x, __bf16& h, __bf16& l) {
  h = (__bf16)x;
  l = (__bf16)(x - (float)h);
}

// -----------------------------------------------------------------------------
// K0 prep: blocks 0..575 split W -> Wh/Wl; blocks 576..959 transpose+split
// ctx [b][c][s] -> cTh/cTl [b][s][c] (full batch).
// -----------------------------------------------------------------------------
__global__ __launch_bounds__(256) void prep_k(const float* __restrict__ W,
                                              const float* __restrict__ ctx,
                                              __bf16* __restrict__ Wh,
                                              __bf16* __restrict__ Wl,
                                              __bf16* __restrict__ cTh,
                                              __bf16* __restrict__ cTl) {
  const int bid = blockIdx.x, t = threadIdx.x;
  __shared__ float tl[64][133];
  if (bid < 576) {
    int idx = bid * 1024 + t * 4;
    float4 v = *(const float4*)(W + idx);
    float vals[4] = {v.x, v.y, v.z, v.w};
    v4bf h, l;
#pragma unroll
    for (int e = 0; e < 4; ++e) {
      __bf16 hh, ll;
      split2(vals[e], hh, ll);
      h[e] = hh;
      l[e] = ll;
    }
    *(v4bf*)(Wh + idx) = h;
    *(v4bf*)(Wl + idx) = l;
    return;
  }
  const int cid = bid - 576;
  const int b = cid / 12, c0 = (cid % 12) * 64;
#pragma unroll
  for (int j = 0; j < 8; ++j) {  // load 64c x 128s, coalesced
    int u = j * 256 + t;
    int c = u >> 5, s4 = (u & 31) * 4;
    *(float4*)&tl[c][s4] =
        *(const float4*)(ctx + ((size_t)b * IDF + c0 + c) * SLN + s4);
  }
  __syncthreads();
#pragma unroll
  for (int j = 0; j < 8; ++j) {  // write [s][c], split
    int u = j * 256 + t;
    int s = u >> 4, c4 = (u & 15) * 4;
    v4bf h, l;
#pragma unroll
    for (int e = 0; e < 4; ++e) {
      __bf16 hh, ll;
      split2(tl[c4 + e][s], hh, ll);
      h[e] = hh;
      l[e] = ll;
    }
    *(v4bf*)(cTh + ((size_t)b * SLN + s) * IDF + c0 + c4) = h;
    *(v4bf*)(cTl + ((size_t)b * SLN + s) * IDF + c0 + c4) = l;
  }
}

// -----------------------------------------------------------------------------
// K1 proj: D[s][o] = sum_c ctxT[s][c] * W[o][c].  Tile 128s x 32o, grid
// (24, 32), 4 waves. 2-deep NAMED reg prefetch + 2x-unrolled loop (static
// indexing). A via chunk-XOR-swizzled LDS; B = Wh/Wl frags 1-deep from L2.
// Outputs STh/STl [b][s][768], Shv [b][o][s].
// -----------------------------------------------------------------------------
__global__ __launch_bounds__(256) void proj_k(const __bf16* __restrict__ cTh,
                                              const __bf16* __restrict__ cTl,
                                              const __bf16* __restrict__ Wh,
                                              const __bf16* __restrict__ Wl,
                                              __bf16* __restrict__ STh,
                                              __bf16* __restrict__ STl,
                                              __bf16* __restrict__ Shv) {
  const int b = blockIdx.y, o0 = blockIdx.x * 32;
  const int t = threadIdx.x, w = t >> 6, lane = t & 63;
  const int lr = lane & 15, lg = lane >> 4;
  const int ws = w >> 1, wq = w & 1;
  __shared__ __bf16 AhL[128][32];
  __shared__ __bf16 AlL[128][32];

  v4f acc[4];
#pragma unroll
  for (int fr = 0; fr < 4; ++fr) acc[fr] = (v4f){0.f, 0.f, 0.f, 0.f};

  const int ra = t >> 1, ca0 = (t & 1) * 2;
  const int swA = (ra >> 1) & 3;
  const int pa0 = (ca0 ^ swA) * 8, pa1 = ((ca0 + 1) ^ swA) * 8;
  const __bf16* pAh = cTh + ((size_t)b * SLN + ra) * IDF + ca0 * 8;
  const __bf16* pAl = cTl + ((size_t)b * SLN + ra) * IDF + ca0 * 8;
  const size_t wOff = (size_t)(o0 + wq * 16 + lr) * IDF + lg * 8;

  uint4 aAh0, aAh1, aAl0, aAl1;   // even tiles
  uint4 bAh0, bAh1, bAl0, bAl1;   // odd tiles
  v8bf bhc, blc, bhn, bln;
  aAh0 = *(const uint4*)(pAh);
  aAh1 = *(const uint4*)(pAh + 8);
  aAl0 = *(const uint4*)(pAl);
  aAl1 = *(const uint4*)(pAl + 8);
  bAh0 = *(const uint4*)(pAh + 32);
  bAh1 = *(const uint4*)(pAh + 40);
  bAl0 = *(const uint4*)(pAl + 32);
  bAl1 = *(const uint4*)(pAl + 40);
  bhc = *(const v8bf*)(Wh + wOff);
  blc = *(const v8bf*)(Wl + wOff);

#define PROJ_BODY(S0, S1, S2, S3, IT)                                          \
  {                                                                            \
    __syncthreads();                                                           \
    *(uint4*)&AhL[ra][pa0] = S0;                                               \
    *(uint4*)&AhL[ra][pa1] = S1;                                               \
    *(uint4*)&AlL[ra][pa0] = S2;                                               \
    *(uint4*)&AlL[ra][pa1] = S3;                                               \
    if ((IT) + 2 < NT) {                                                       \
      S0 = *(const uint4*)(pAh + ((IT) + 2) * 32);                             \
      S1 = *(const uint4*)(pAh + ((IT) + 2) * 32 + 8);                         \
      S2 = *(const uint4*)(pAl + ((IT) + 2) * 32);                             \
      S3 = *(const uint4*)(pAl + ((IT) + 2) * 32 + 8);                         \
    }                                                                          \
    if ((IT) + 1 < NT) {                                                       \
      bhn = *(const v8bf*)(Wh + wOff + ((IT) + 1) * 32);                       \
      bln = *(const v8bf*)(Wl + wOff + ((IT) + 1) * 32);                       \
    }                                                                          \
    __syncthreads();                                                           \
    _Pragma("unroll") for (int fr = 0; fr < 4; ++fr) {                         \
      const int r = ws * 64 + fr * 16 + lr;                                    \
      const int pp = (lg ^ ((r >> 1) & 3)) * 8;                                \
      v8bf ah = *(const v8bf*)&AhL[r][pp];                                     \
      v8bf al = *(const v8bf*)&AlL[r][pp];                                     \
      acc[fr] = MFMA16(ah, bhc, acc[fr], 0, 0, 0);                             \
      acc[fr] = MFMA16(ah, blc, acc[fr], 0, 0, 0);                             \
      acc[fr] = MFMA16(al, bhc, acc[fr], 0, 0, 0);                             \
    }                                                                          \
    bhc = bhn;                                                                 \
    blc = bln;                                                                 \
  }

  for (int it2 = 0; it2 < NT / 2; ++it2) {
    const int itE = it2 * 2;
    PROJ_BODY(aAh0, aAh1, aAl0, aAl1, itE);
    PROJ_BODY(bAh0, bAh1, bAl0, bAl1, itE + 1);
  }
#undef PROJ_BODY

  const int o = o0 + wq * 16 + lr;
#pragma unroll
  for (int fr = 0; fr < 4; ++fr) {
    __bf16 hp[4];
#pragma unroll
    for (int r = 0; r < 4; ++r) {
      int s = ws * 64 + fr * 16 + lg * 4 + r;
      __bf16 h, l;
      split2(acc[fr][r], h, l);
      STh[((size_t)b * SLN + s) * IDF + o] = h;
      STl[((size_t)b * SLN + s) * IDF + o] = l;
      hp[r] = h;
    }
    *(v4bf*)(Shv + ((size_t)b * IDF + o) * SLN + ws * 64 + fr * 16 + lg * 4) =
        (v4bf){hp[0], hp[1], hp[2], hp[3]};
  }
}

// -----------------------------------------------------------------------------
// K2 qkpv (fused): 512 threads = 8 waves, grid (16 q-tiles of 64, 32 b).
// Phase 1 (QK): round-9 structure — wave (wq = w&3 q-16, sh = w>>2 s-half);
//   A-hi/lo staged by thread halves into XOR-swizzled LDS; input f32 tile;
//   2-deep NAMED reg prefetch. Softmax cross-wave via LDS.
// Phase 2: P -> PL LDS tile [64 q][128 s] bf16, 16B-group XOR swizzle
//   (group ^= q&15) — reads conflict-free, writes <=4-way one-time.
// Phase 3 (PV): wave (qfp = w&1 pair of q-frags, islab = (w>>1)*192);
//   P-frags hoisted (8 v8bf), Shv streamed from L2, float4 stores to wc.
//   Same kt order + same bf16 P values as old pv_k => bit-identical wc.
// -----------------------------------------------------------------------------
__global__ __launch_bounds__(512, 4) void qkpv_k(const float* __restrict__ input,
                                                 const __bf16* __restrict__ STh,
                                                 const __bf16* __restrict__ STl,
                                                 const __bf16* __restrict__ Shv,
                                                 const int* __restrict__ mask,
                                                 float* __restrict__ wc,
                                                 float* __restrict__ attn_out) {
  const int b = blockIdx.y, q0 = blockIdx.x * 64;
  const int t = threadIdx.x, w = t >> 6, lane = t & 63;
  const int lr = lane & 15, lg = lane >> 4;
  const int wq = w & 3, sh = w >> 2;
  __shared__ __bf16 AhL[128][32];
  __shared__ __bf16 AlL[128][32];
  __shared__ __align__(16) float tiL[32][66];
  __shared__ float msk[SLN];
  __shared__ float redm[2][4][16], reds[2][4][16];
  __shared__ __align__(16) __bf16 PL[64 * 128];  // swizzled P tile
  char* const PLb = (char*)PL;
  if (t < SLN) msk[t] = -10000.0f * (float)mask[b * SLN + t];

  v4f acc[4];
#pragma unroll
  for (int fr = 0; fr < 4; ++fr) acc[fr] = (v4f){0.f, 0.f, 0.f, 0.f};

  const int u = t & 255;
  const int ra = u >> 1, ca0 = (u & 1) * 2;
  const int swA = (ra >> 1) & 3;
  const int pa0 = (ca0 ^ swA) * 8, pa1 = ((ca0 + 1) ^ swA) * 8;
  const __bf16* pA =
      (((t < 256) ? STh : STl) + ((size_t)b * SLN + ra) * IDF) + ca0 * 8;
  __bf16* dA = (t < 256) ? &AhL[0][0] : &AlL[0][0];
  __bf16* dA0 = dA + ra * 32 + pa0;
  __bf16* dA1 = dA + ra * 32 + pa1;
  const int rb = t >> 4, cb = (t & 15) * 4;
  const float* pIn = input + ((size_t)b * IDF + rb) * QLN + q0 + cb;

  // named 2-deep prefetch sets
  uint4 aA0, aA1, bA0, bA1;
  float4 aT, bT;
  aA0 = *(const uint4*)(pA);
  aA1 = *(const uint4*)(pA + 8);
  aT  = *(const float4*)(pIn);
  bA0 = *(const uint4*)(pA + 32);
  bA1 = *(const uint4*)(pA + 40);
  bT  = *(const float4*)(pIn + (size_t)32 * QLN);

#define QK_BODY(S0, S1, ST_, IT)                                               \
  {                                                                            \
    __syncthreads();                                                           \
    *(uint4*)dA0 = S0;                                                         \
    *(uint4*)dA1 = S1;                                                         \
    *(float2*)&tiL[rb][cb]     = make_float2(ST_.x, ST_.y);                    \
    *(float2*)&tiL[rb][cb + 2] = make_float2(ST_.z, ST_.w);                    \
    if ((IT) + 2 < NT) {                                                       \
      S0 = *(const uint4*)(pA + ((IT) + 2) * 32);                              \
      S1 = *(const uint4*)(pA + ((IT) + 2) * 32 + 8);                          \
      ST_ = *(const float4*)(pIn + (size_t)((IT) + 2) * 32 * QLN);             \
    }                                                                          \
    __syncthreads();                                                           \
    v8bf bh, bl;                                                               \
    _Pragma("unroll") for (int e = 0; e < 8; ++e) {                            \
      __bf16 h, l;                                                             \
      split2(tiL[lg * 8 + e][wq * 16 + lr], h, l);                             \
      bh[e] = h;                                                               \
      bl[e] = l;                                                               \
    }                                                                          \
    _Pragma("unroll") for (int fr = 0; fr < 4; ++fr) {                         \
      const int r = sh * 64 + fr * 16 + lr;                                    \
      const int pp = (lg ^ ((r >> 1) & 3)) * 8;                                \
      v8bf ah = *(const v8bf*)&AhL[r][pp];                                     \
      v8bf al = *(const v8bf*)&AlL[r][pp];                                     \
      acc[fr] = MFMA16(ah, bh, acc[fr], 0, 0, 0);                              \
      acc[fr] = MFMA16(ah, bl, acc[fr], 0, 0, 0);                              \
      acc[fr] = MFMA16(al, bh, acc[fr], 0, 0, 0);                              \
    }                                                                          \
  }

  for (int it2 = 0; it2 < NT / 2; ++it2) {
    const int itE = it2 * 2;
    QK_BODY(aA0, aA1, aT, itE);
    QK_BODY(bA0, bA1, bT, itE + 1);
  }
#undef QK_BODY

  // softmax over s=128 for q = q0 + wq*16 + lr; wave owns 64 s (half sh)
  const int q = q0 + wq * 16 + lr;
  float mx = -3.0e38f;
#pragma unroll
  for (int fr = 0; fr < 4; ++fr)
#pragma unroll
    for (int r = 0; r < 4; ++r) {
      acc[fr][r] += msk[sh * 64 + fr * 16 + lg * 4 + r];
      mx = fmaxf(mx, acc[fr][r]);
    }
  mx = fmaxf(mx, __shfl_xor(mx, 16));
  mx = fmaxf(mx, __shfl_xor(mx, 32));
  if (lg == 0) redm[sh][wq][lr] = mx;
  __syncthreads();
  mx = fmaxf(redm[0][wq][lr], redm[1][wq][lr]);
  float sum = 0.f;
#pragma unroll
  for (int fr = 0; fr < 4; ++fr)
#pragma unroll
    for (int r = 0; r < 4; ++r) {
      float e = __expf(acc[fr][r] - mx);
      acc[fr][r] = e;
      sum += e;
    }
  sum += __shfl_xor(sum, 16);
  sum += __shfl_xor(sum, 32);
  if (lg == 0) reds[sh][wq][lr] = sum;
  __syncthreads();
  const float inv = 1.0f / (reds[0][wq][lr] + reds[1][wq][lr]);
  const int qloc = wq * 16 + lr;
#pragma unroll
  for (int fr = 0; fr < 4; ++fr) {
    __bf16 hp[4];
#pragma unroll
    for (int r = 0; r < 4; ++r) {
      float p = acc[fr][r] * inv;
      attn_out[((size_t)b * SLN + sh * 64 + fr * 16 + lg * 4 + r) * QLN + q] = p;
      hp[r] = (__bf16)p;
    }
    // PL swizzled write: s0 = sh*64+fr*16+lg*4; 16B-group g = s0>>3, g ^= q&15
    const int g = (sh * 8 + fr * 2 + (lg >> 1)) ^ lr;
    *(v4bf*)(PLb + qloc * 256 + g * 16 + (lg & 1) * 8) =
        (v4bf){hp[0], hp[1], hp[2], hp[3]};
  }
  __syncthreads();

  // ---- PV phase: wave -> (q-frag pair qfp, i-slab of 192) ----
  const int qfp = (w & 1) * 2;
  const int islab = (w >> 2 << 1 | ((w >> 1) & 1)) * 192;  // (w>>1)*192
  v8bf pa0v[4], pa1v[4];
#pragma unroll
  for (int kt = 0; kt < 4; ++kt) {
    const int g0 = (kt * 4 + lg) ^ lr;
    pa0v[kt] = *(const v8bf*)(PLb + (qfp * 16 + lr) * 256 + g0 * 16);
    pa1v[kt] = *(const v8bf*)(PLb + ((qfp + 1) * 16 + lr) * 256 + g0 * 16);
  }
  const __bf16* pShv = Shv + ((size_t)b * IDF + islab + lr) * SLN + lg * 8;
  float* pWc = wc + ((size_t)b * IDF + islab + lr) * QLN + q0;
#pragma unroll 2
  for (int ifr = 0; ifr < 12; ++ifr) {
    v4f a0 = (v4f){0.f, 0.f, 0.f, 0.f};
    v4f a1 = (v4f){0.f, 0.f, 0.f, 0.f};
#pragma unroll
    for (int kt = 0; kt < 4; ++kt) {
      v8bf bb = *(const v8bf*)(pShv + (size_t)(ifr * 16) * SLN + kt * 32);
      a0 = MFMA16(pa0v[kt], bb, a0, 0, 0, 0);
      a1 = MFMA16(pa1v[kt], bb, a1, 0, 0, 0);
    }
    *(float4*)(pWc + (size_t)(ifr * 16) * QLN + qfp * 16 + lg * 4) =
        make_float4(a0[0], a0[1], a0[2], a0[3]);
    *(float4*)(pWc + (size_t)(ifr * 16) * QLN + (qfp + 1) * 16 + lg * 4) =
        make_float4(a1[0], a1[1], a1[2], a1[3]);
  }
}

// -----------------------------------------------------------------------------
extern "C" void kernel_launch(void* const* d_in, const int* in_sizes, int n_in,
                              void* d_out, int out_size, void* d_ws, size_t ws_size,
                              hipStream_t stream) {
  const float* input   = (const float*)d_in[0];  // [B, IDF, 32, 32]
  const float* context = (const float*)d_in[1];  // [B, CDF, SL]
  const int*   mask    = (const int*)d_in[2];    // [B, SL]
  const float* w_conv  = (const float*)d_in[3];  // [IDF, CDF]

  float* out      = (float*)d_out;
  float* wc       = out;                          // [B, IDF, QL]
  float* attn_out = out + (size_t)NB * IDF * QLN; // [B, SL, QL]

  // Scratch plan:
  //  - wc output region doubles as scratch for cTh|cTl|Wh|Wl (14.9 MB); all
  //    dead before qkpv's PV phase writes wc.
  //  - d_ws: STh | STl | Shv = 9,437,184 bf16 = 18,874,368 B (< 29.36 MB OK).
  const size_t SE = (size_t)NB * SLN * IDF;  // 3,145,728
  const size_t WE = (size_t)IDF * IDF;       // 589,824
  __bf16* wsb = (__bf16*)d_ws;
  __bf16* STh = wsb;
  __bf16* STl = STh + SE;
  __bf16* Shv = STl + SE;
  __bf16* scr = (__bf16*)wc;  // scratch in output region
  __bf16* cTh = scr;
  __bf16* cTl = cTh + SE;
  __bf16* Wh  = cTl + SE;
  __bf16* Wl  = Wh + WE;

  prep_k<<<960, 256, 0, stream>>>(w_conv, context, Wh, Wl, cTh, cTl);
  proj_k<<<dim3(24, NB), 256, 0, stream>>>(cTh, cTl, Wh, Wl, STh, STl, Shv);
  qkpv_k<<<dim3(16, NB), 512, 0, stream>>>(input, STh, STl, Shv, mask, wc,
                                           attn_out);
}